// Round 4
// baseline (100.600 us; speedup 1.0000x reference)
//
#include <hip/hip_runtime.h>
#include <hip/hip_bf16.h>

#define NB 4
#define NH 12
#define SEQ 4096
#define DIM 64
#define LOG2E 1.4426950408889634f

typedef __attribute__((ext_vector_type(8))) short short8;
typedef __attribute__((ext_vector_type(4))) float f32x4;
typedef __attribute__((ext_vector_type(4))) unsigned short ushort4v;

static __device__ __forceinline__ unsigned short f2bf(float f) {
    unsigned int u = __builtin_bit_cast(unsigned int, f);
    u = u + 0x7FFFu + ((u >> 16) & 1u);   // RNE (inputs finite)
    return (unsigned short)(u >> 16);
}

__global__ __launch_bounds__(1024, 4)
void blk_attn(const float* __restrict__ Q, const float* __restrict__ K,
              const float* __restrict__ V, const float* __restrict__ M,
              float* __restrict__ O) {
    int bid = blockIdx.x;
    bid = (bid & 7) * 192 + (bid >> 3);   // XCD-aware bijective swizzle (1536 % 8 == 0)

    const int j  = bid & 31;   // 128-query group
    const int bh = bid >> 5;
    const int b  = bh / NH;

    const size_t base = (size_t)bh * SEQ * DIM;
    const float* Qp = Q + base + (size_t)j * 128 * DIM;
    const float* Kp = K + base;
    const float* Vp = V + base;
    const float* Mp = M + (size_t)b * SEQ;
    float*       Op = O + base + (size_t)j * 128 * DIM;

    const int tid  = threadIdx.x;
    const int w    = tid >> 6;      // wave 0..15
    const int qg   = w >> 1;        // query group 0..7 (16 rows)
    const int h    = w & 1;         // key half: tiles [12h, 12h+12)
    const int lane = tid & 63;
    const int lo   = lane & 15;
    const int hi   = lane >> 4;

    // union span [kb0, kb0+384): window0 = tiles 0..15, window1 = tiles 8..23
    const int  kb0 = (j == 0) ? 0 : (j == 31 ? SEQ - 384 : 128 * j - 128);
    const bool md  = (j != 0) && (j != 31);
    const float wt0 = (j == 31) ? 0.f : (md ? 0.5f : 1.f);
    const float wt1 = (j == 0)  ? 0.f : (md ? 0.5f : 1.f);

    // 132 KB LDS, 1 block/CU, 16 waves (4/SIMD with <=128 VGPR)
    __shared__ __align__(16) unsigned char smem[135168];
    auto Ks = (unsigned short (*)[64])(smem);                // [384][64], key-major
    auto Vt = (unsigned short (*)[384])(smem + 49152);       // [64][384], d-major
    auto Pw = (unsigned short (*)[16][64])(smem + 98304);    // [16 waves][16 q][64 k]
    auto Sx = (float (*)[8][16][4])(smem + 131072);          // [h][qg][q][m,S0,S1,-]
    auto Opart = (float (*)[16][68])(smem);                  // [8][16][68] alias (Ks dead)

    // ---- Q fragments, scaled by log2e/sqrt(64) ----
    short8 qa[2];
    {
        const float qs = 0.125f * LOG2E;
        const float* qr = Qp + (size_t)(qg * 16 + lo) * DIM + hi * 8;
        #pragma unroll
        for (int s = 0; s < 2; ++s) {
            f32x4 a = *reinterpret_cast<const f32x4*>(qr + 32 * s);
            f32x4 c = *reinterpret_cast<const f32x4*>(qr + 32 * s + 4);
            short8 t;
            t[0] = (short)f2bf(a[0] * qs); t[1] = (short)f2bf(a[1] * qs);
            t[2] = (short)f2bf(a[2] * qs); t[3] = (short)f2bf(a[3] * qs);
            t[4] = (short)f2bf(c[0] * qs); t[5] = (short)f2bf(c[1] * qs);
            t[6] = (short)f2bf(c[2] * qs); t[7] = (short)f2bf(c[3] * qs);
            qa[s] = t;
        }
    }

    // ---- stage K: 384 rows (conflict-free swizzled ushort4 writes) ----
    {
        const int c4 = (tid & 15) * 4;
        const int r0 = tid >> 4;                 // 0..63
        #pragma unroll
        for (int rr = 0; rr < 6; ++rr) {
            const int row = r0 + 64 * rr;
            f32x4 kv = *reinterpret_cast<const f32x4*>(Kp + (size_t)(kb0 + row) * DIM + c4);
            ushort4v kk;
            kk[0] = f2bf(kv[0]); kk[1] = f2bf(kv[1]);
            kk[2] = f2bf(kv[2]); kk[3] = f2bf(kv[3]);
            *reinterpret_cast<ushort4v*>(&Ks[row][c4 ^ (8 * (row & 7))]) = kk;
        }
    }
    // ---- stage V transposed: 4x4 register transpose ----
    {
        const int quad = tid & 3;
        const int colq = (tid >> 2) & 15;
        #pragma unroll
        for (int it = 0; it < 2; ++it) {
            const int kg = w + 16 * it;          // wave-uniform branch
            if (kg < 24) {
                const int k0 = kg * 16 + quad * 4;
                f32x4 vr[4];
                #pragma unroll
                for (int kk = 0; kk < 4; ++kk)
                    vr[kk] = *reinterpret_cast<const f32x4*>(
                        Vp + (size_t)(kb0 + k0 + kk) * DIM + 4 * colq);
                #pragma unroll
                for (int i = 0; i < 4; ++i) {
                    const int d = 4 * colq + i;
                    ushort4v o;
                    o[0] = f2bf(vr[0][i]); o[1] = f2bf(vr[1][i]);
                    o[2] = f2bf(vr[2][i]); o[3] = f2bf(vr[3][i]);
                    *reinterpret_cast<ushort4v*>(&Vt[d][k0 ^ (8 * (d & 7))]) = o;
                }
            }
        }
    }
    __syncthreads();

    // ---- QK^T: this wave's 12 tiles ----
    f32x4 st[12];
    #pragma unroll
    for (int l = 0; l < 12; ++l) { st[l][0]=0.f; st[l][1]=0.f; st[l][2]=0.f; st[l][3]=0.f; }
    const int krow0 = 192 * h;
    __builtin_amdgcn_s_setprio(1);
    #pragma unroll
    for (int s = 0; s < 2; ++s)
        #pragma unroll
        for (int l = 0; l < 12; ++l) {
            short8 kf = *reinterpret_cast<const short8*>(
                &Ks[krow0 + 16 * l + lo][(s * 32 + hi * 8) ^ (8 * (lo & 7))]);
            st[l] = __builtin_amdgcn_mfma_f32_16x16x32_bf16(qa[s], kf, st[l], 0, 0, 0);
        }
    __builtin_amdgcn_s_setprio(0);

    // ---- mask (pre-scaled by log2e) ----
    #pragma unroll
    for (int l = 0; l < 12; ++l) {
        const float mv = Mp[kb0 + krow0 + 16 * l + lo] * LOG2E;
        #pragma unroll
        for (int r = 0; r < 4; ++r) st[l][r] += mv;
    }

    // ---- local softmax: one exp pass vs local max (union-max trick) ----
    float mloc[4], sAll[4], sPrt[4];
    #pragma unroll
    for (int r = 0; r < 4; ++r) {
        float m = fmaxf(fmaxf(fmaxf(fmaxf(st[0][r], st[1][r]), fmaxf(st[2][r], st[3][r])),
                              fmaxf(fmaxf(st[4][r], st[5][r]), fmaxf(st[6][r], st[7][r]))),
                        fmaxf(fmaxf(st[8][r], st[9][r]), fmaxf(st[10][r], st[11][r])));
        m = fmaxf(m, __shfl_xor(m, 1));
        m = fmaxf(m, __shfl_xor(m, 2));
        m = fmaxf(m, __shfl_xor(m, 4));
        m = fmaxf(m, __shfl_xor(m, 8));
        mloc[r] = m;
    }
    #pragma unroll
    for (int l = 0; l < 12; ++l)
        #pragma unroll
        for (int r = 0; r < 4; ++r)
            st[l][r] = exp2f(st[l][r] - mloc[r]);
    #pragma unroll
    for (int r = 0; r < 4; ++r) {
        float sp = (h == 0)
            ? (st[8][r] + st[9][r]) + (st[10][r] + st[11][r])    // W1 part of half 0
            : (st[0][r] + st[1][r]) + (st[2][r] + st[3][r]);     // W0 part of half 1
        float sa = ((st[0][r] + st[1][r]) + (st[2][r] + st[3][r]))
                 + ((st[4][r] + st[5][r]) + (st[6][r] + st[7][r]))
                 + ((st[8][r] + st[9][r]) + (st[10][r] + st[11][r]));
        sa += __shfl_xor(sa, 1); sa += __shfl_xor(sa, 2);
        sa += __shfl_xor(sa, 4); sa += __shfl_xor(sa, 8);
        sp += __shfl_xor(sp, 1); sp += __shfl_xor(sp, 2);
        sp += __shfl_xor(sp, 4); sp += __shfl_xor(sp, 8);
        sAll[r] = sa; sPrt[r] = sp;
    }

    // ---- exchange (m, S0, S1) with partner half ----
    if (lo == 0) {
        #pragma unroll
        for (int r = 0; r < 4; ++r) {
            const int q = 4 * hi + r;
            Sx[h][qg][q][0] = mloc[r];
            Sx[h][qg][q][1] = (h == 0) ? sAll[r] : sPrt[r];   // S0 contribution
            Sx[h][qg][q][2] = (h == 0) ? sPrt[r] : sAll[r];   // S1 contribution
        }
    }
    __syncthreads();

    float b0[4], b1[4];
    #pragma unroll
    for (int r = 0; r < 4; ++r) {
        const int q = 4 * hi + r;
        const float mo  = Sx[1 - h][qg][q][0];
        const float s0o = Sx[1 - h][qg][q][1];
        const float s1o = Sx[1 - h][qg][q][2];
        const float s0l = (h == 0) ? sAll[r] : sPrt[r];
        const float s1l = (h == 0) ? sPrt[r] : sAll[r];
        const float mu  = fmaxf(mloc[r], mo);
        const float scm = exp2f(mloc[r] - mu);
        const float sco = exp2f(mo - mu);
        const float S0  = s0l * scm + s0o * sco;
        const float S1  = s1l * scm + s1o * sco;
        b0[r] = wt0 * scm / S0;
        b1[r] = wt1 * scm / S1;
    }

    // ---- PV: 3 passes of 64 keys, P' pre-weighted (both windows folded) ----
    f32x4 acc[4];
    #pragma unroll
    for (int dt = 0; dt < 4; ++dt) { acc[dt][0]=0.f; acc[dt][1]=0.f; acc[dt][2]=0.f; acc[dt][3]=0.f; }

    #pragma unroll
    for (int kq = 0; kq < 3; ++kq) {
        #pragma unroll
        for (int tt = 0; tt < 4; ++tt) {
            const int l = 4 * kq + tt;
            #pragma unroll
            for (int r = 0; r < 4; ++r) {
                const int q = 4 * hi + r;
                const float coef = (h == 0) ? (b0[r] + (l >= 8 ? b1[r] : 0.f))
                                            : (b1[r] + (l < 4  ? b0[r] : 0.f));
                Pw[w][q][(tt * 16 + lo) ^ (8 * (q & 7))] = f2bf(st[l][r] * coef);
            }
        }
        // per-wave private buffer; compiler orders ds_write->ds_read (may-alias)
        __builtin_amdgcn_s_setprio(1);
        #pragma unroll
        for (int s = 0; s < 2; ++s) {
            short8 pf = *reinterpret_cast<const short8*>(
                &Pw[w][lo][(s * 32 + hi * 8) ^ (8 * (lo & 7))]);
            #pragma unroll
            for (int dt = 0; dt < 4; ++dt) {
                const int kcol = 192 * h + 64 * kq + s * 32 + hi * 8;
                short8 vf = *reinterpret_cast<const short8*>(
                    &Vt[dt * 16 + lo][kcol ^ (8 * (lo & 7))]);
                acc[dt] = __builtin_amdgcn_mfma_f32_16x16x32_bf16(pf, vf, acc[dt], 0, 0, 0);
            }
        }
        __builtin_amdgcn_s_setprio(0);
    }

    // ---- combine halves through LDS (Opart aliases dead Ks region) ----
    if (h == 0) {
        #pragma unroll
        for (int dt = 0; dt < 4; ++dt)
            #pragma unroll
            for (int r = 0; r < 4; ++r)
                Opart[qg][4 * hi + r][dt * 16 + lo] = acc[dt][r];
    }
    __syncthreads();
    if (h == 1) {
        #pragma unroll
        for (int dt = 0; dt < 4; ++dt)
            #pragma unroll
            for (int r = 0; r < 4; ++r) {
                const float v = acc[dt][r] + Opart[qg][4 * hi + r][dt * 16 + lo];
                Op[(size_t)(qg * 16 + 4 * hi + r) * DIM + dt * 16 + lo] = v;
            }
    }
}

extern "C" void kernel_launch(void* const* d_in, const int* in_sizes, int n_in,
                              void* d_out, int out_size, void* d_ws, size_t ws_size,
                              hipStream_t stream) {
    const float* Q = (const float*)d_in[0];
    const float* K = (const float*)d_in[1];
    const float* V = (const float*)d_in[2];
    const float* M = (const float*)d_in[3];
    float* O = (float*)d_out;
    blk_attn<<<dim3(NB * NH * (SEQ / 128)), dim3(1024), 0, stream>>>(Q, K, V, M, O);
}

// Round 6
// 88.283 us; speedup vs baseline: 1.1395x; 1.1395x over previous
//
#include <hip/hip_runtime.h>
#include <hip/hip_bf16.h>

#define NB 4
#define NH 12
#define SEQ 4096
#define DIM 64
#define LOG2E 1.4426950408889634f

typedef __attribute__((ext_vector_type(8))) short short8;
typedef __attribute__((ext_vector_type(4))) float f32x4;
typedef __attribute__((ext_vector_type(2))) unsigned int u32x2;

static __device__ __forceinline__ unsigned int pk2(float a, float b) {
    float2 t; t.x = a; t.y = b;
    union { __hip_bfloat162 h; unsigned int u; } x;
    x.h = __float22bfloat162_rn(t);
    return x.u;
}
static __device__ __forceinline__ short8 mk8(unsigned int a, unsigned int b,
                                             unsigned int c, unsigned int d) {
    union { unsigned int u[4]; short8 s; } x;
    x.u[0] = a; x.u[1] = b; x.u[2] = c; x.u[3] = d;
    return x.s;
}

__global__ __launch_bounds__(1024)
void blk_attn(const float* __restrict__ Q, const float* __restrict__ K,
              const float* __restrict__ V, const float* __restrict__ M,
              float* __restrict__ O) {
    int bid = blockIdx.x;
    bid = (bid & 7) * 192 + (bid >> 3);   // XCD-aware bijective swizzle (1536 % 8 == 0)

    const int j  = bid & 31;
    const int bh = bid >> 5;
    const int b  = bh / NH;

    const size_t base = (size_t)bh * SEQ * DIM;
    const float* Qp = Q + base + (size_t)j * 128 * DIM;
    const float* Kp = K + base;
    const float* Vp = V + base;
    const float* Mp = M + (size_t)b * SEQ;
    float*       Op = O + base + (size_t)j * 128 * DIM;

    const int tid  = threadIdx.x;
    const int w    = tid >> 6;      // wave 0..15
    const int qg   = w >> 1;        // query group (16 rows)
    const int h    = w & 1;         // key half: tiles [12h, 12h+12)
    const int lane = tid & 63;
    const int lo   = lane & 15;
    const int hi   = lane >> 4;

    // union span [kb0, kb0+384): window0 = tiles 0..15, window1 = tiles 8..23
    const int  kb0 = (j == 0) ? 0 : (j == 31 ? SEQ - 384 : 128 * j - 128);
    const bool md  = (j != 0) && (j != 31);
    const float wt0 = (j == 31) ? 0.f : (md ? 0.5f : 1.f);
    const float wt1 = (j == 0)  ? 0.f : (md ? 0.5f : 1.f);

    // ---- LDS layout (120320 B total) ----
    __shared__ __align__(16) unsigned char smem[120320];
    auto Ks  = (unsigned short (*)[64])(smem);              // [384][64]: K[key][d ^ 8*(key&7)]
    auto Vt  = (unsigned short (*)[384])(smem + 49152);     // [64][384]: V^T[d][k ^ 8*((d^(d>>2))&7)]
    auto Pwd = (unsigned int (*)[16][16])(smem + 98304);    // [16 waves][16 q][16 dw]
    auto Sx  = (float (*)[8][16][4])(smem + 114688);        // [h][qg][q][m,S0c,S1c,-]
    auto Ml  = (float*)(smem + 118784);                     // [384] mask
    auto Opart = (float (*)[16][68])(smem);                 // alias over dead Ks

    // ---- mask -> LDS ----
    if (tid < 96) {
        f32x4 mv = *reinterpret_cast<const f32x4*>(Mp + kb0 + 4 * tid);
        *reinterpret_cast<f32x4*>(&Ml[4 * tid]) = mv;
    }

    // ---- Q fragments, scaled by log2e/8 (same regs serve as B-operand) ----
    short8 qa[2];
    {
        const float qs = 0.125f * LOG2E;
        const float* qr = Qp + (size_t)(qg * 16 + lo) * DIM + hi * 8;
        #pragma unroll
        for (int s = 0; s < 2; ++s) {
            f32x4 a = *reinterpret_cast<const f32x4*>(qr + 32 * s);
            f32x4 c = *reinterpret_cast<const f32x4*>(qr + 32 * s + 4);
            qa[s] = mk8(pk2(a[0] * qs, a[1] * qs), pk2(a[2] * qs, a[3] * qs),
                        pk2(c[0] * qs, c[1] * qs), pk2(c[2] * qs, c[3] * qs));
        }
    }

    // ---- stage K: 8 rows x 8 d-chunks per wave-instr, b128 writes, conflict-free ----
    {
        const int c8 = lane & 7;
        const int r8 = lane >> 3;
        #pragma unroll
        for (int rr = 0; rr < 3; ++rr) {
            const int row = 8 * w + r8 + 128 * rr;          // row & 7 == r8
            const float* kp = Kp + (size_t)(kb0 + row) * DIM + 8 * c8;
            f32x4 a = *reinterpret_cast<const f32x4*>(kp);
            f32x4 c = *reinterpret_cast<const f32x4*>(kp + 4);
            short8 kk = mk8(pk2(a[0], a[1]), pk2(a[2], a[3]),
                            pk2(c[0], c[1]), pk2(c[2], c[3]));
            *reinterpret_cast<short8*>(&Ks[row][(8 * c8) ^ (8 * r8)]) = kk;
        }
    }
    // ---- stage V^T: 4x4 register transpose, b64 writes, conflict-free swizzle ----
    {
        const int quad = lane & 3;
        const int colq = lane >> 2;    // 0..15
        #pragma unroll
        for (int it = 0; it < 2; ++it) {
            const int kg = w + 16 * it;
            if (kg < 24) {
                const int k0 = 16 * kg + 4 * quad;
                f32x4 vr[4];
                #pragma unroll
                for (int kk = 0; kk < 4; ++kk)
                    vr[kk] = *reinterpret_cast<const f32x4*>(
                        Vp + (size_t)(kb0 + k0 + kk) * DIM + 4 * colq);
                #pragma unroll
                for (int i = 0; i < 4; ++i) {
                    const int d  = 4 * colq + i;
                    const int gd = (d ^ (d >> 2)) & 7;
                    u32x2 o;
                    o[0] = pk2(vr[0][i], vr[1][i]);
                    o[1] = pk2(vr[2][i], vr[3][i]);
                    *reinterpret_cast<u32x2*>(&Vt[d][k0 ^ (8 * gd)]) = o;
                }
            }
        }
    }
    __syncthreads();

    // ---- QK^T swapped: st[l] = K_tile * Q  ->  D[key=4hi+r(+16l)][q=lo] ----
    f32x4 st[12];
    #pragma unroll
    for (int l = 0; l < 12; ++l) { st[l][0]=0.f; st[l][1]=0.f; st[l][2]=0.f; st[l][3]=0.f; }
    const int krow0 = 192 * h;
    const int kswz  = 8 * (lo & 7);
    __builtin_amdgcn_s_setprio(1);
    #pragma unroll
    for (int s = 0; s < 2; ++s)
        #pragma unroll
        for (int l = 0; l < 12; ++l) {
            short8 kf = *reinterpret_cast<const short8*>(
                &Ks[krow0 + 16 * l + lo][(32 * s + 8 * hi) ^ kswz]);
            st[l] = __builtin_amdgcn_mfma_f32_16x16x32_bf16(kf, qa[s], st[l], 0, 0, 0);
        }
    __builtin_amdgcn_s_setprio(0);

    // ---- mask add (keys = rows now) ----
    #pragma unroll
    for (int l = 0; l < 12; ++l) {
        f32x4 mv = *reinterpret_cast<const f32x4*>(&Ml[krow0 + 16 * l + 4 * hi]);
        #pragma unroll
        for (int r = 0; r < 4; ++r) st[l][r] = fmaf(mv[r], LOG2E, st[l][r]);
    }

    // ---- softmax, lane-local per query (only xor-16/32 shuffles) ----
    float mx = st[0][0];
    #pragma unroll
    for (int l = 0; l < 12; ++l)
        #pragma unroll
        for (int r = 0; r < 4; ++r) mx = fmaxf(mx, st[l][r]);
    mx = fmaxf(mx, __shfl_xor(mx, 16));
    mx = fmaxf(mx, __shfl_xor(mx, 32));
    #pragma unroll
    for (int l = 0; l < 12; ++l)
        #pragma unroll
        for (int r = 0; r < 4; ++r) st[l][r] = exp2f(st[l][r] - mx);

    float sA = 0.f, sB = 0.f, sC = 0.f;   // tiles 0-3 / 4-7 / 8-11 (static idx)
    #pragma unroll
    for (int l = 0; l < 4; ++l)
        #pragma unroll
        for (int r = 0; r < 4; ++r) {
            sA += st[l][r]; sB += st[l + 4][r]; sC += st[l + 8][r];
        }
    float sa = sA + sB + sC;
    float sp = h ? sA : sC;               // overlap part (W1-of-h0 / W0-of-h1)
    sa += __shfl_xor(sa, 16); sa += __shfl_xor(sa, 32);
    sp += __shfl_xor(sp, 16); sp += __shfl_xor(sp, 32);

    if (hi == 0) {
        Sx[h][qg][lo][0] = mx;
        Sx[h][qg][lo][1] = h ? sp : sa;   // S0 contribution
        Sx[h][qg][lo][2] = h ? sa : sp;   // S1 contribution
    }
    __syncthreads();

    const float mo  = Sx[1 - h][qg][lo][0];
    const float s0o = Sx[1 - h][qg][lo][1];
    const float s1o = Sx[1 - h][qg][lo][2];
    const float s0l = h ? sp : sa;
    const float s1l = h ? sa : sp;
    const float mu  = fmaxf(mx, mo);
    const float scm = exp2f(mx - mu);
    const float sco = exp2f(mo - mu);
    const float S0  = fmaf(s0l, scm, s0o * sco);
    const float S1  = fmaf(s1l, scm, s1o * sco);
    const float b0  = wt0 * scm / S0;
    const float b1  = wt1 * scm / S1;
    float cz[3];
    cz[0] = h ? (b0 + b1) : b0;           // l 0-3
    cz[1] = h ? b1 : b0;                  // l 4-7
    cz[2] = h ? b1 : (b0 + b1);           // l 8-11

    // ---- PV over this half's 192 keys: packed P writes + swapped-layout A-frag ----
    f32x4 acc[4];
    #pragma unroll
    for (int dt = 0; dt < 4; ++dt) { acc[dt][0]=0.f; acc[dt][1]=0.f; acc[dt][2]=0.f; acc[dt][3]=0.f; }
    const int pvswz = 4 * ((lo >> 1) & 3);

    #pragma unroll
    for (int kq = 0; kq < 6; ++kq) {
        #pragma unroll
        for (int l1 = 0; l1 < 2; ++l1) {
            const int l = 2 * kq + l1;
            const float c = cz[l >> 2];
            #pragma unroll
            for (int rp = 0; rp < 2; ++rp) {
                Pwd[w][lo][(8 * l1 + 2 * hi + rp) ^ pvswz] =
                    pk2(st[l][2 * rp] * c, st[l][2 * rp + 1] * c);
            }
        }
        // per-wave private buffer; HW DS is in-order per wave
        short8 pf = *reinterpret_cast<const short8*>(&Pwd[w][lo][(4 * hi) ^ pvswz]);
        __builtin_amdgcn_s_setprio(1);
        #pragma unroll
        for (int dt = 0; dt < 4; ++dt) {
            const int d  = 16 * dt + lo;
            const int gd = (d ^ (d >> 2)) & 7;
            short8 vf = *reinterpret_cast<const short8*>(
                &Vt[d][(krow0 + 32 * kq + 8 * hi) ^ (8 * gd)]);
            acc[dt] = __builtin_amdgcn_mfma_f32_16x16x32_bf16(pf, vf, acc[dt], 0, 0, 0);
        }
        __builtin_amdgcn_s_setprio(0);
    }

    // ---- combine halves (Opart aliases dead Ks) ----
    if (h == 0) {
        #pragma unroll
        for (int dt = 0; dt < 4; ++dt)
            #pragma unroll
            for (int r = 0; r < 4; ++r)
                Opart[qg][4 * hi + r][16 * dt + lo] = acc[dt][r];
    }
    __syncthreads();
    if (h == 1) {
        #pragma unroll
        for (int dt = 0; dt < 4; ++dt)
            #pragma unroll
            for (int r = 0; r < 4; ++r) {
                const float v = acc[dt][r] + Opart[qg][4 * hi + r][16 * dt + lo];
                Op[(size_t)(qg * 16 + 4 * hi + r) * DIM + 16 * dt + lo] = v;
            }
    }
}

extern "C" void kernel_launch(void* const* d_in, const int* in_sizes, int n_in,
                              void* d_out, int out_size, void* d_ws, size_t ws_size,
                              hipStream_t stream) {
    const float* Q = (const float*)d_in[0];
    const float* K = (const float*)d_in[1];
    const float* V = (const float*)d_in[2];
    const float* M = (const float*)d_in[3];
    float* O = (float*)d_out;
    blk_attn<<<dim3(NB * NH * (SEQ / 128)), dim3(1024), 0, stream>>>(Q, K, V, M, O);
}